// Round 5
// baseline (386.320 us; speedup 1.0000x reference)
//
#include <hip/hip_runtime.h>
#include <math.h>

#define D_MODEL 1024
#define D_STATE 128
#define SEQ_LEN 4096
#define BATCH 4
#define NTOK (BATCH * SEQ_LEN)      // 16384
#define LN_EPS 1e-3f
#define NCHUNK 128                  // chunks per batch
#define LCHUNK (SEQ_LEN / NCHUNK)   // 32

typedef __attribute__((ext_vector_type(8))) short bf16x8;
typedef __attribute__((ext_vector_type(4))) float f32x4;

__device__ __forceinline__ short f2bf(float f) {
    union { float f; unsigned u; } v; v.f = f;
    unsigned r = v.u + 0x7FFFu + ((v.u >> 16) & 1u);   // RNE
    return (short)(r >> 16);
}
__device__ __forceinline__ float bf2f(short s) {
    union { unsigned u; float f; } v; v.u = ((unsigned)(unsigned short)s) << 16;
    return v.f;
}

// ------- fused pre-pass: LayerNorm (blocks 0..16383) + weight transposes -----
__global__ __launch_bounds__(256) void pre_kernel(
    const float* __restrict__ x, const float* __restrict__ gamma,
    const float* __restrict__ beta, short* __restrict__ xn_bf,
    const float* __restrict__ W_in, const float* __restrict__ W_xs,
    const float* __restrict__ W_B, const float* __restrict__ W_C,
    const float* __restrict__ W_so, const float* __restrict__ W_out,
    const float* __restrict__ bB, const float* __restrict__ bC,
    short* __restrict__ W_inT, short* __restrict__ W3T,
    short* __restrict__ W_soT, short* __restrict__ W_outT,
    float* __restrict__ bias3) {
    if (blockIdx.x < NTOK) {
        // ---- LayerNorm row ----
        int row = blockIdx.x;
        const float4* xr = (const float4*)(x + (size_t)row * D_MODEL);
        float4 v = xr[threadIdx.x];
        float s1 = v.x + v.y + v.z + v.w;
        float s2 = v.x * v.x + v.y * v.y + v.z * v.z + v.w * v.w;
        for (int off = 32; off; off >>= 1) {
            s1 += __shfl_down(s1, off);
            s2 += __shfl_down(s2, off);
        }
        __shared__ float ls1[4], ls2[4];
        int wid = threadIdx.x >> 6, lane = threadIdx.x & 63;
        if (lane == 0) { ls1[wid] = s1; ls2[wid] = s2; }
        __syncthreads();
        s1 = ls1[0] + ls1[1] + ls1[2] + ls1[3];
        s2 = ls2[0] + ls2[1] + ls2[2] + ls2[3];
        float mu = s1 * (1.0f / D_MODEL);
        float var = s2 * (1.0f / D_MODEL) - mu * mu;
        float r = rsqrtf(var + LN_EPS);
        float4 g = ((const float4*)gamma)[threadIdx.x];
        float4 b = ((const float4*)beta)[threadIdx.x];
        short4 o;
        o.x = f2bf((v.x - mu) * r * g.x + b.x);
        o.y = f2bf((v.y - mu) * r * g.y + b.y);
        o.z = f2bf((v.z - mu) * r * g.z + b.z);
        o.w = f2bf((v.w - mu) * r * g.w + b.w);
        ((short4*)(xn_bf + (size_t)row * D_MODEL))[threadIdx.x] = o;
        return;
    }
    // ---- weight transpose+bf16 tiles ----
    int blk = blockIdx.x - NTOK;
    const float* in; short* out; int K, N, tile;
    if (blk < 1024)      { in = W_in;  out = W_inT;           K = 1024; N = 1024; tile = blk; }
    else if (blk < 1152) { in = W_xs;  out = W3T;             K = 1024; N = 128;  tile = blk - 1024; }
    else if (blk < 1280) { in = W_B;   out = W3T + 128*1024;  K = 1024; N = 128;  tile = blk - 1152; }
    else if (blk < 1408) { in = W_C;   out = W3T + 256*1024;  K = 1024; N = 128;  tile = blk - 1280; }
    else if (blk < 1536) { in = W_so;  out = W_soT;           K = 128;  N = 1024; tile = blk - 1408; }
    else if (blk < 2560) { in = W_out; out = W_outT;          K = 1024; N = 1024; tile = blk - 1536; }
    else {
        int t = threadIdx.x;
        for (int n = t; n < 384; n += 256)
            bias3[n] = (n < 128) ? 0.f : ((n < 256) ? bB[n - 128] : bC[n - 256]);
        return;
    }
    __shared__ float t32[32][33];
    int ntiles = N / 32;
    int nb = (tile % ntiles) * 32, kb = (tile / ntiles) * 32;
    int tx = threadIdx.x & 31, ty = threadIdx.x >> 5;   // 32 x 8
#pragma unroll
    for (int i = 0; i < 4; ++i)
        t32[ty + 8 * i][tx] = in[(size_t)(kb + ty + 8 * i) * N + nb + tx];
    __syncthreads();
#pragma unroll
    for (int i = 0; i < 4; ++i)
        out[(size_t)(nb + ty + 8 * i) * K + kb + tx] = f2bf(t32[tx][ty + 8 * i]);
}

// ---------------- bf16 MFMA GEMM: BK=64, XOR-swizzled LDS, XCD swizzle ------
template<int HAS_BIAS, int HAS_ADD, int ADD_BF, int HAS_SCALE, int OUT_F32, int OUT_BF, int SWZ>
__global__ __launch_bounds__(256, 4) void gemm_bf16(
    const short* __restrict__ A, const short* __restrict__ BT,
    const float* __restrict__ bias,
    const float* __restrict__ addf, const short* __restrict__ addb,
    const float* __restrict__ addscale,
    float* __restrict__ Cf, short* __restrict__ Cbf,
    int Mt, int Nt, int K) {
    __shared__ short As[128 * 64];   // 16 KiB
    __shared__ short Bs[128 * 64];   // 16 KiB
    int p = blockIdx.x;
    int mtile, ntile;
    if (SWZ) {           // xcd = p&7; each XCD runs (m, n=0..7) consecutively
        int k = p & 7, q = p >> 3;
        ntile = q & 7;
        mtile = k + 8 * (q >> 3);
    } else {
        mtile = p % Mt;
        ntile = p / Mt;
    }
    int m0 = mtile * 128, n0 = ntile * 128;
    int N = Nt * 128;
    int tid = threadIdx.x;
    int lane = tid & 63;
    int w = tid >> 6;
    int quad = lane >> 4, r16 = lane & 15;
    int wm = (w & 1) * 64, wn = (w >> 1) * 64;

    f32x4 acc[4][4] = {};

    for (int k0 = 0; k0 < K; k0 += 64) {
#pragma unroll
        for (int it = 0; it < 4; ++it) {
            int seg = it * 256 + tid;          // 0..1023
            int row = seg >> 3, slot = seg & 7;
            int kc8 = slot ^ (row & 7);
            const short* gp = A + (size_t)(m0 + row) * K + k0 + kc8 * 8;
            __builtin_amdgcn_global_load_lds(
                (const __attribute__((address_space(1))) unsigned*)gp,
                (__attribute__((address_space(3))) unsigned*)(As + seg * 8), 16, 0, 0);
        }
#pragma unroll
        for (int it = 0; it < 4; ++it) {
            int seg = it * 256 + tid;
            int row = seg >> 3, slot = seg & 7;
            int kc8 = slot ^ (row & 7);
            const short* gp = BT + (size_t)(n0 + row) * K + k0 + kc8 * 8;
            __builtin_amdgcn_global_load_lds(
                (const __attribute__((address_space(1))) unsigned*)gp,
                (__attribute__((address_space(3))) unsigned*)(Bs + seg * 8), 16, 0, 0);
        }
        __syncthreads();

        const short* abase = As + (wm + r16) * 64;
        const short* bbase = Bs + (wn + r16) * 64;
        int sw = r16 & 7;
#pragma unroll
        for (int kk = 0; kk < 2; ++kk) {
            int phys = ((quad + 4 * kk) ^ sw) * 8;
            bf16x8 af[4], bfr[4];
#pragma unroll
            for (int i = 0; i < 4; ++i) af[i] = *(const bf16x8*)(abase + i * 16 * 64 + phys);
#pragma unroll
            for (int j = 0; j < 4; ++j) bfr[j] = *(const bf16x8*)(bbase + j * 16 * 64 + phys);
#pragma unroll
            for (int i = 0; i < 4; ++i)
#pragma unroll
                for (int j = 0; j < 4; ++j)
                    acc[i][j] = __builtin_amdgcn_mfma_f32_16x16x32_bf16(af[i], bfr[j], acc[i][j], 0, 0, 0);
        }
        __syncthreads();
    }

#pragma unroll
    for (int i = 0; i < 4; ++i) {
#pragma unroll
        for (int j = 0; j < 4; ++j) {
            int col = n0 + wn + j * 16 + r16;
            float bv = HAS_BIAS ? bias[col] : 0.f;
            float sc = HAS_SCALE ? addscale[col] : 1.f;
#pragma unroll
            for (int pr = 0; pr < 4; ++pr) {
                int row = m0 + wm + i * 16 + quad * 4 + pr;
                float v = acc[i][j][pr] + bv;
                if (HAS_ADD) {
                    float av = ADD_BF ? bf2f(addb[(size_t)row * N + col])
                                      : addf[(size_t)row * N + col];
                    v += sc * av;
                }
                if (OUT_F32) Cf[(size_t)row * N + col] = v;
                if (OUT_BF) Cbf[(size_t)row * N + col] = f2bf(v);
            }
        }
    }
}

// ------------- single-pass chunked scan with decoupled lookback -------------
// h[t] = a*h[t-1] + u[t]; ys = h * C_sel. Ticket-based rank (no dispatch-order
// assumption): rank r only waits on ranks < r, which have already started.
#define FLAG_AGG 1
#define FLAG_INC 2
__global__ __launch_bounds__(128) void scan_fused(
    const float* __restrict__ s3, const float* __restrict__ A_log,
    float* __restrict__ Ebuf, float* __restrict__ Gbuf,
    int* __restrict__ flags, int* __restrict__ ticket,
    short* __restrict__ ys_bf) {
    __shared__ int sh;
    int s = threadIdx.x;   // state index 0..127
    if (s == 0)
        sh = __hip_atomic_fetch_add(ticket, 1, __ATOMIC_RELAXED, __HIP_MEMORY_SCOPE_AGENT);
    __syncthreads();
    int rank = sh;
    __syncthreads();
    int b = rank >> 7;          // rank / NCHUNK
    int c = rank & (NCHUNK - 1);

    float A = -expf(A_log[s]);
    float a = expf(A);
    float pw = expf(A * (float)LCHUNK);
    size_t base = (size_t)b * SEQ_LEN + (size_t)c * LCHUNK;

    // local scan, h kept in registers
    float h[LCHUNK];
    float hh = 0.f;
#pragma unroll
    for (int i = 0; i < LCHUNK; ++i) {
        size_t r = base + i;
        float u = s3[r * 384 + s] * s3[r * 384 + 128 + s];
        hh = a * hh + u;
        h[i] = hh;
    }
    float E = hh;
    size_t idx = ((size_t)b * NCHUNK + c) * 128 + s;
    float carry = 0.f;

    if (c == 0) {
        __hip_atomic_store(&Gbuf[idx], E, __ATOMIC_RELAXED, __HIP_MEMORY_SCOPE_AGENT);
        __syncthreads();   // drains vmcnt before flag release
        if (s == 0)
            __hip_atomic_store(&flags[b * NCHUNK], FLAG_INC, __ATOMIC_RELEASE, __HIP_MEMORY_SCOPE_AGENT);
    } else {
        __hip_atomic_store(&Ebuf[idx], E, __ATOMIC_RELAXED, __HIP_MEMORY_SCOPE_AGENT);
        __syncthreads();
        if (s == 0)
            __hip_atomic_store(&flags[b * NCHUNK + c], FLAG_AGG, __ATOMIC_RELEASE, __HIP_MEMORY_SCOPE_AGENT);
        // lookback
        float pwk = 1.f;
        int j = c - 1;
        while (true) {
            if (s == 0) {
                int f;
                do {
                    f = __hip_atomic_load(&flags[b * NCHUNK + j], __ATOMIC_ACQUIRE, __HIP_MEMORY_SCOPE_AGENT);
                } while (f == 0);
                sh = f;
            }
            __syncthreads();
            int f = sh;
            __syncthreads();
            size_t jdx = ((size_t)b * NCHUNK + j) * 128 + s;
            if (f == FLAG_INC) {
                float G = __hip_atomic_load(&Gbuf[jdx], __ATOMIC_RELAXED, __HIP_MEMORY_SCOPE_AGENT);
                carry += pwk * G;
                break;
            } else {
                float Ej = __hip_atomic_load(&Ebuf[jdx], __ATOMIC_RELAXED, __HIP_MEMORY_SCOPE_AGENT);
                carry += pwk * Ej;
                pwk *= pw;
                --j;
            }
        }
        float G = E + pw * carry;
        __hip_atomic_store(&Gbuf[idx], G, __ATOMIC_RELAXED, __HIP_MEMORY_SCOPE_AGENT);
        __syncthreads();
        if (s == 0)
            __hip_atomic_store(&flags[b * NCHUNK + c], FLAG_INC, __ATOMIC_RELEASE, __HIP_MEMORY_SCOPE_AGENT);
    }

    // apply carry, multiply by C_sel, emit bf16
    float ap = a;
#pragma unroll
    for (int i = 0; i < LCHUNK; ++i) {
        size_t r = base + i;
        float hv = h[i] + ap * carry;
        ap *= a;
        ys_bf[r * 128 + s] = f2bf(hv * s3[r * 384 + 256 + s]);
    }
}

extern "C" void kernel_launch(void* const* d_in, const int* in_sizes, int n_in,
                              void* d_out, int out_size, void* d_ws, size_t ws_size,
                              hipStream_t stream) {
    const float* x     = (const float*)d_in[0];
    const float* ln_g  = (const float*)d_in[1];
    const float* ln_b  = (const float*)d_in[2];
    const float* W_in  = (const float*)d_in[3];
    const float* b_in  = (const float*)d_in[4];
    const float* W_xs  = (const float*)d_in[5];
    const float* W_B   = (const float*)d_in[6];
    const float* b_B   = (const float*)d_in[7];
    const float* W_C   = (const float*)d_in[8];
    const float* b_C   = (const float*)d_in[9];
    const float* A_log = (const float*)d_in[10];
    const float* Dvec  = (const float*)d_in[11];
    const float* W_so  = (const float*)d_in[12];
    const float* W_out = (const float*)d_in[13];
    const float* b_out = (const float*)d_in[14];
    float* out = (float*)d_out;

    // ---- workspace carve (bytes) ----
    char* w = (char*)d_ws;
    size_t off = 0;
    short* xn_bf = (short*)(w + off);                       // region 0: 32 MiB
    short* ys_bf = (short*)(w + off + 8388608);             //   (xn dead after g1)
    off += (size_t)NTOK * D_MODEL * 2;
    short* z_bf  = (short*)(w + off);                       // region 1: 32 MiB
    off += (size_t)NTOK * D_MODEL * 2;
    short* y1_bf = (short*)(w + off);                       // region 2: 32 MiB
    off += (size_t)NTOK * D_MODEL * 2;
    float* s3    = (float*)(w + off); off += (size_t)NTOK * 384 * 4;       // 24 MiB
    float* Ebuf  = (float*)(w + off); off += (size_t)BATCH * NCHUNK * 128 * 4;
    float* Gbuf  = (float*)(w + off); off += (size_t)BATCH * NCHUNK * 128 * 4;
    int*   scanctl = (int*)(w + off); off += 4096;          // flags[512] + ticket
    short* W_inT  = (short*)(w + off); off += (size_t)D_MODEL * D_MODEL * 2;
    short* W3T    = (short*)(w + off); off += (size_t)384 * D_MODEL * 2;
    short* W_soT  = (short*)(w + off); off += (size_t)D_MODEL * D_STATE * 2;
    short* W_outT = (short*)(w + off); off += (size_t)D_MODEL * D_MODEL * 2;
    float* bias3  = (float*)(w + off); off += 2048;
    int* flags  = scanctl;
    int* ticket = scanctl + BATCH * NCHUNK;

    // zero scan control (ws is poisoned before every timed launch)
    hipMemsetAsync(scanctl, 0, 4096, stream);

    // ---- 0) fused LN + weight prep ----
    pre_kernel<<<NTOK + 2561, 256, 0, stream>>>(
        x, ln_g, ln_b, xn_bf, W_in, W_xs, W_B, W_C, W_so, W_out,
        b_B, b_C, W_inT, W3T, W_soT, W_outT, bias3);

    const int Mt = NTOK / 128;   // 128
    // ---- 1) z = xn @ W_in + b_in  (bf16) ----
    gemm_bf16<1, 0, 0, 0, 0, 1, 1><<<Mt * 8, 256, 0, stream>>>(
        xn_bf, W_inT, b_in, nullptr, nullptr, nullptr,
        nullptr, z_bf, Mt, 8, D_MODEL);

    // ---- 2) s3 = z @ [W_xs|W_B|W_C] + bias3  (f32) ----
    gemm_bf16<1, 0, 0, 0, 1, 0, 0><<<Mt * 3, 256, 0, stream>>>(
        z_bf, W3T, bias3, nullptr, nullptr, nullptr,
        s3, nullptr, Mt, 3, D_MODEL);

    // ---- 3) single-pass scan (exact), fused *C_sel -> ys_bf ----
    scan_fused<<<BATCH * NCHUNK, 128, 0, stream>>>(s3, A_log, Ebuf, Gbuf,
                                                   flags, ticket, ys_bf);

    // ---- 4) y1 = ys @ W_so + D*z  (bf16 out, bf16 addmat) ----
    gemm_bf16<0, 1, 1, 1, 0, 1, 1><<<Mt * 8, 256, 0, stream>>>(
        ys_bf, W_soT, nullptr, nullptr, z_bf, Dvec,
        nullptr, y1_bf, Mt, 8, D_STATE);

    // ---- 5) out = y1 @ W_out + b_out + x (f32 residual) ----
    gemm_bf16<1, 1, 0, 0, 1, 0, 1><<<Mt * 8, 256, 0, stream>>>(
        y1_bf, W_outT, b_out, x, nullptr, nullptr,
        out, nullptr, Mt, 8, D_MODEL);
}

// Round 6
// 284.375 us; speedup vs baseline: 1.3585x; 1.3585x over previous
//
#include <hip/hip_runtime.h>
#include <math.h>

#define D_MODEL 1024
#define D_STATE 128
#define SEQ_LEN 4096
#define BATCH 4
#define NTOK (BATCH * SEQ_LEN)      // 16384
#define LN_EPS 1e-3f
#define NCHUNK 128                  // chunks per batch
#define LCHUNK (SEQ_LEN / NCHUNK)   // 32

typedef __attribute__((ext_vector_type(8))) short bf16x8;
typedef __attribute__((ext_vector_type(4))) float f32x4;

__device__ __forceinline__ short f2bf(float f) {
    union { float f; unsigned u; } v; v.f = f;
    unsigned r = v.u + 0x7FFFu + ((v.u >> 16) & 1u);   // RNE
    return (short)(r >> 16);
}
__device__ __forceinline__ float bf2f(short s) {
    union { unsigned u; float f; } v; v.u = ((unsigned)(unsigned short)s) << 16;
    return v.f;
}

// ------- fused pre-pass: LayerNorm (blocks 0..16383) + weight transposes -----
__global__ __launch_bounds__(256) void pre_kernel(
    const float* __restrict__ x, const float* __restrict__ gamma,
    const float* __restrict__ beta, short* __restrict__ xn_bf,
    const float* __restrict__ W_in, const float* __restrict__ W_xs,
    const float* __restrict__ W_B, const float* __restrict__ W_C,
    const float* __restrict__ W_so, const float* __restrict__ W_out,
    const float* __restrict__ bB, const float* __restrict__ bC,
    short* __restrict__ W_inT, short* __restrict__ W3T,
    short* __restrict__ W_soT, short* __restrict__ W_outT,
    float* __restrict__ bias3) {
    if (blockIdx.x < NTOK) {
        // ---- LayerNorm row ----
        int row = blockIdx.x;
        const float4* xr = (const float4*)(x + (size_t)row * D_MODEL);
        float4 v = xr[threadIdx.x];
        float s1 = v.x + v.y + v.z + v.w;
        float s2 = v.x * v.x + v.y * v.y + v.z * v.z + v.w * v.w;
        for (int off = 32; off; off >>= 1) {
            s1 += __shfl_down(s1, off);
            s2 += __shfl_down(s2, off);
        }
        __shared__ float ls1[4], ls2[4];
        int wid = threadIdx.x >> 6, lane = threadIdx.x & 63;
        if (lane == 0) { ls1[wid] = s1; ls2[wid] = s2; }
        __syncthreads();
        s1 = ls1[0] + ls1[1] + ls1[2] + ls1[3];
        s2 = ls2[0] + ls2[1] + ls2[2] + ls2[3];
        float mu = s1 * (1.0f / D_MODEL);
        float var = s2 * (1.0f / D_MODEL) - mu * mu;
        float r = rsqrtf(var + LN_EPS);
        float4 g = ((const float4*)gamma)[threadIdx.x];
        float4 b = ((const float4*)beta)[threadIdx.x];
        short4 o;
        o.x = f2bf((v.x - mu) * r * g.x + b.x);
        o.y = f2bf((v.y - mu) * r * g.y + b.y);
        o.z = f2bf((v.z - mu) * r * g.z + b.z);
        o.w = f2bf((v.w - mu) * r * g.w + b.w);
        ((short4*)(xn_bf + (size_t)row * D_MODEL))[threadIdx.x] = o;
        return;
    }
    // ---- weight transpose+bf16 tiles ----
    int blk = blockIdx.x - NTOK;
    const float* in; short* out; int K, N, tile;
    if (blk < 1024)      { in = W_in;  out = W_inT;           K = 1024; N = 1024; tile = blk; }
    else if (blk < 1152) { in = W_xs;  out = W3T;             K = 1024; N = 128;  tile = blk - 1024; }
    else if (blk < 1280) { in = W_B;   out = W3T + 128*1024;  K = 1024; N = 128;  tile = blk - 1152; }
    else if (blk < 1408) { in = W_C;   out = W3T + 256*1024;  K = 1024; N = 128;  tile = blk - 1280; }
    else if (blk < 1536) { in = W_so;  out = W_soT;           K = 128;  N = 1024; tile = blk - 1408; }
    else if (blk < 2560) { in = W_out; out = W_outT;          K = 1024; N = 1024; tile = blk - 1536; }
    else {
        int t = threadIdx.x;
        for (int n = t; n < 384; n += 256)
            bias3[n] = (n < 128) ? 0.f : ((n < 256) ? bB[n - 128] : bC[n - 256]);
        return;
    }
    __shared__ float t32[32][33];
    int ntiles = N / 32;
    int nb = (tile % ntiles) * 32, kb = (tile / ntiles) * 32;
    int tx = threadIdx.x & 31, ty = threadIdx.x >> 5;   // 32 x 8
#pragma unroll
    for (int i = 0; i < 4; ++i)
        t32[ty + 8 * i][tx] = in[(size_t)(kb + ty + 8 * i) * N + nb + tx];
    __syncthreads();
#pragma unroll
    for (int i = 0; i < 4; ++i)
        out[(size_t)(nb + ty + 8 * i) * K + kb + tx] = f2bf(t32[tx][ty + 8 * i]);
}

// ---------------- bf16 MFMA GEMM: BK=64, XOR-swizzled LDS, XCD swizzle ------
template<int HAS_BIAS, int HAS_ADD, int ADD_BF, int HAS_SCALE, int OUT_F32, int OUT_BF, int SWZ>
__global__ __launch_bounds__(256, 4) void gemm_bf16(
    const short* __restrict__ A, const short* __restrict__ BT,
    const float* __restrict__ bias,
    const float* __restrict__ addf, const short* __restrict__ addb,
    const float* __restrict__ addscale,
    float* __restrict__ Cf, short* __restrict__ Cbf,
    int Mt, int Nt, int K) {
    __shared__ short As[128 * 64];   // 16 KiB
    __shared__ short Bs[128 * 64];   // 16 KiB
    int p = blockIdx.x;
    int mtile, ntile;
    if (SWZ) {           // xcd = p&7; each XCD runs (m, n=0..7) consecutively
        int k = p & 7, q = p >> 3;
        ntile = q & 7;
        mtile = k + 8 * (q >> 3);
    } else {
        mtile = p % Mt;
        ntile = p / Mt;
    }
    int m0 = mtile * 128, n0 = ntile * 128;
    int N = Nt * 128;
    int tid = threadIdx.x;
    int lane = tid & 63;
    int w = tid >> 6;
    int quad = lane >> 4, r16 = lane & 15;
    int wm = (w & 1) * 64, wn = (w >> 1) * 64;

    f32x4 acc[4][4] = {};

    for (int k0 = 0; k0 < K; k0 += 64) {
#pragma unroll
        for (int it = 0; it < 4; ++it) {
            int seg = it * 256 + tid;          // 0..1023
            int row = seg >> 3, slot = seg & 7;
            int kc8 = slot ^ (row & 7);
            const short* gp = A + (size_t)(m0 + row) * K + k0 + kc8 * 8;
            __builtin_amdgcn_global_load_lds(
                (const __attribute__((address_space(1))) unsigned*)gp,
                (__attribute__((address_space(3))) unsigned*)(As + seg * 8), 16, 0, 0);
        }
#pragma unroll
        for (int it = 0; it < 4; ++it) {
            int seg = it * 256 + tid;
            int row = seg >> 3, slot = seg & 7;
            int kc8 = slot ^ (row & 7);
            const short* gp = BT + (size_t)(n0 + row) * K + k0 + kc8 * 8;
            __builtin_amdgcn_global_load_lds(
                (const __attribute__((address_space(1))) unsigned*)gp,
                (__attribute__((address_space(3))) unsigned*)(Bs + seg * 8), 16, 0, 0);
        }
        __syncthreads();

        const short* abase = As + (wm + r16) * 64;
        const short* bbase = Bs + (wn + r16) * 64;
        int sw = r16 & 7;
#pragma unroll
        for (int kk = 0; kk < 2; ++kk) {
            int phys = ((quad + 4 * kk) ^ sw) * 8;
            bf16x8 af[4], bfr[4];
#pragma unroll
            for (int i = 0; i < 4; ++i) af[i] = *(const bf16x8*)(abase + i * 16 * 64 + phys);
#pragma unroll
            for (int j = 0; j < 4; ++j) bfr[j] = *(const bf16x8*)(bbase + j * 16 * 64 + phys);
#pragma unroll
            for (int i = 0; i < 4; ++i)
#pragma unroll
                for (int j = 0; j < 4; ++j)
                    acc[i][j] = __builtin_amdgcn_mfma_f32_16x16x32_bf16(af[i], bfr[j], acc[i][j], 0, 0, 0);
        }
        __syncthreads();
    }

#pragma unroll
    for (int i = 0; i < 4; ++i) {
#pragma unroll
        for (int j = 0; j < 4; ++j) {
            int col = n0 + wn + j * 16 + r16;
            float bv = HAS_BIAS ? bias[col] : 0.f;
            float sc = HAS_SCALE ? addscale[col] : 1.f;
#pragma unroll
            for (int pr = 0; pr < 4; ++pr) {
                int row = m0 + wm + i * 16 + quad * 4 + pr;
                float v = acc[i][j][pr] + bv;
                if (HAS_ADD) {
                    float av = ADD_BF ? bf2f(addb[(size_t)row * N + col])
                                      : addf[(size_t)row * N + col];
                    v += sc * av;
                }
                if (OUT_F32) Cf[(size_t)row * N + col] = v;
                if (OUT_BF) Cbf[(size_t)row * N + col] = f2bf(v);
            }
        }
    }
}

// ---------------- Chunked linear scan, 3-phase (exact FFT-conv replacement) --
__global__ __launch_bounds__(128) void scan_p1(const float* __restrict__ s3,
                                               const float* __restrict__ A_log,
                                               float* __restrict__ hbuf,
                                               float* __restrict__ Ebuf) {
    int s = threadIdx.x;
    int c = blockIdx.x, b = blockIdx.y;
    float a = expf(-expf(A_log[s]));
    float h = 0.f;
    size_t base = (size_t)b * SEQ_LEN + (size_t)c * LCHUNK;
#pragma unroll 8
    for (int i = 0; i < LCHUNK; ++i) {
        size_t r = base + i;
        float u = s3[r * 384 + s] * s3[r * 384 + 128 + s];
        h = a * h + u;
        hbuf[r * 128 + s] = h;
    }
    Ebuf[((size_t)b * NCHUNK + c) * 128 + s] = h;
}

__global__ __launch_bounds__(512) void scan_p2(const float* __restrict__ A_log,
                                               const float* __restrict__ Ebuf,
                                               float* __restrict__ Gbuf) {
    int tid = threadIdx.x;
    int b = tid >> 7, s = tid & 127;
    float pw = expf(-expf(A_log[s]) * (float)LCHUNK);
    float G = 0.f;
    for (int c0 = 0; c0 < NCHUNK; c0 += 16) {
        float e[16];
#pragma unroll
        for (int t = 0; t < 16; ++t)
            e[t] = Ebuf[((size_t)b * NCHUNK + c0 + t) * 128 + s];
#pragma unroll
        for (int t = 0; t < 16; ++t) {
            G = pw * G + e[t];
            Gbuf[((size_t)b * NCHUNK + c0 + t) * 128 + s] = G;
        }
    }
}

__global__ __launch_bounds__(128) void scan_p3(const float* __restrict__ s3,
                                               const float* __restrict__ A_log,
                                               const float* __restrict__ hbuf,
                                               const float* __restrict__ Gbuf,
                                               short* __restrict__ ys_bf) {
    int s = threadIdx.x;
    int c = blockIdx.x, b = blockIdx.y;
    float a = expf(-expf(A_log[s]));
    float carry = (c == 0) ? 0.f : Gbuf[((size_t)b * NCHUNK + c - 1) * 128 + s];
    float p = a;
    size_t base = (size_t)b * SEQ_LEN + (size_t)c * LCHUNK;
#pragma unroll 8
    for (int i = 0; i < LCHUNK; ++i) {
        size_t r = base + i;
        float h = hbuf[r * 128 + s] + p * carry;
        p *= a;
        ys_bf[r * 128 + s] = f2bf(h * s3[r * 384 + 256 + s]);
    }
}

extern "C" void kernel_launch(void* const* d_in, const int* in_sizes, int n_in,
                              void* d_out, int out_size, void* d_ws, size_t ws_size,
                              hipStream_t stream) {
    const float* x     = (const float*)d_in[0];
    const float* ln_g  = (const float*)d_in[1];
    const float* ln_b  = (const float*)d_in[2];
    const float* W_in  = (const float*)d_in[3];
    const float* b_in  = (const float*)d_in[4];
    const float* W_xs  = (const float*)d_in[5];
    const float* W_B   = (const float*)d_in[6];
    const float* b_B   = (const float*)d_in[7];
    const float* W_C   = (const float*)d_in[8];
    const float* b_C   = (const float*)d_in[9];
    const float* A_log = (const float*)d_in[10];
    const float* Dvec  = (const float*)d_in[11];
    const float* W_so  = (const float*)d_in[12];
    const float* W_out = (const float*)d_in[13];
    const float* b_out = (const float*)d_in[14];
    float* out = (float*)d_out;

    // ---- workspace carve (bytes) ----
    char* w = (char*)d_ws;
    size_t off = 0;
    short* xn_bf = (short*)(w + off);                       // region 0: 32 MiB
    float* hbuf  = (float*)(w + off);                       //   reuses region 0 after GEMM1
    short* ys_bf = (short*)(w + off + 8388608);             //   after hbuf (8 MiB)
    off += (size_t)NTOK * D_MODEL * 2;
    short* z_bf  = (short*)(w + off);                       // region 1: 32 MiB
    off += (size_t)NTOK * D_MODEL * 2;
    short* y1_bf = (short*)(w + off);                       // region 2: 32 MiB
    off += (size_t)NTOK * D_MODEL * 2;
    float* s3    = (float*)(w + off); off += (size_t)NTOK * 384 * 4;       // 24 MiB
    float* Ebuf  = (float*)(w + off); off += (size_t)BATCH * NCHUNK * 128 * 4;
    float* Gbuf  = (float*)(w + off); off += (size_t)BATCH * NCHUNK * 128 * 4;
    short* W_inT  = (short*)(w + off); off += (size_t)D_MODEL * D_MODEL * 2;
    short* W3T    = (short*)(w + off); off += (size_t)384 * D_MODEL * 2;
    short* W_soT  = (short*)(w + off); off += (size_t)D_MODEL * D_STATE * 2;
    short* W_outT = (short*)(w + off); off += (size_t)D_MODEL * D_MODEL * 2;
    float* bias3  = (float*)(w + off); off += 2048;

    // ---- 0) fused LN + weight prep ----
    pre_kernel<<<NTOK + 2561, 256, 0, stream>>>(
        x, ln_g, ln_b, xn_bf, W_in, W_xs, W_B, W_C, W_so, W_out,
        b_B, b_C, W_inT, W3T, W_soT, W_outT, bias3);

    const int Mt = NTOK / 128;   // 128
    // ---- 1) z = xn @ W_in + b_in  (bf16) ----
    gemm_bf16<1, 0, 0, 0, 0, 1, 1><<<Mt * 8, 256, 0, stream>>>(
        xn_bf, W_inT, b_in, nullptr, nullptr, nullptr,
        nullptr, z_bf, Mt, 8, D_MODEL);

    // ---- 2) s3 = z @ [W_xs|W_B|W_C] + bias3  (f32) ----
    gemm_bf16<1, 0, 0, 0, 1, 0, 0><<<Mt * 3, 256, 0, stream>>>(
        z_bf, W3T, bias3, nullptr, nullptr, nullptr,
        s3, nullptr, Mt, 3, D_MODEL);

    // ---- 3) chunked scan (fp32 exact), fused *C_sel -> ys_bf ----
    scan_p1<<<dim3(NCHUNK, BATCH), 128, 0, stream>>>(s3, A_log, hbuf, Ebuf);
    scan_p2<<<1, 512, 0, stream>>>(A_log, Ebuf, Gbuf);
    scan_p3<<<dim3(NCHUNK, BATCH), 128, 0, stream>>>(s3, A_log, hbuf, Gbuf, ys_bf);

    // ---- 4) y1 = ys @ W_so + D*z  (bf16 out, bf16 addmat) ----
    gemm_bf16<0, 1, 1, 1, 0, 1, 1><<<Mt * 8, 256, 0, stream>>>(
        ys_bf, W_soT, nullptr, nullptr, z_bf, Dvec,
        nullptr, y1_bf, Mt, 8, D_STATE);

    // ---- 5) out = y1 @ W_out + b_out + x (f32 residual) ----
    gemm_bf16<1, 1, 0, 0, 1, 0, 1><<<Mt * 8, 256, 0, stream>>>(
        y1_bf, W_outT, b_out, x, nullptr, nullptr,
        out, nullptr, Mt, 8, D_MODEL);
}